// Round 1
// baseline (250.766 us; speedup 1.0000x reference)
//
#include <hip/hip_runtime.h>

// Splice: out[m][j] = a[m/R][j]      for j <  sa
//                   = b[m][j - sa]   for sa <= j < sa+sb
//                   = dst[m][j]      for j >= sa+sb
//
// Structure: one block per row-GROUP (R=4 rows sharing a_row).
//   - 512 blocks x 1024 threads; team t (256 threads) handles row 4g+t.
//   - seq_a/seq_b loaded once per group (not once per 17 blocks).
//   - a_row read by all 4 teams through the same CU's L1/L2 (intra-block
//     reuse -> no cross-XCD refetch of a).
//   - Row split into 3 uniform loops: pure-A copy, pure-dst tail copy,
//     tiny mixed region (scalar). Copy loops unrolled x4 for MLP
//     (64 B in flight per lane instead of 16 B).
//   - dst loads / out stores are nontemporal (single-use streaming,
//     203 MB) so they don't evict the reused a rows from L2/L3.

typedef int v4i __attribute__((ext_vector_type(4)));

__global__ __launch_bounds__(1024) void splice_kernel(
    const int* __restrict__ dst,
    const int* __restrict__ a,
    const int* __restrict__ b,
    const int* __restrict__ seq_a,
    const int* __restrict__ seq_b,
    int* __restrict__ out,
    int LEN_OUT, int LEN_A, int LEN_B, int repeat)
{
    const int g    = blockIdx.x;            // row-group index (= a row)
    const int team = threadIdx.x >> 8;      // 0..repeat-1 -> row within group
    const int tid  = threadIdx.x & 255;     // lane within team
    const int m    = g * repeat + team;     // output row

    const int sa    = seq_a[g];             // block-uniform
    const int sb    = seq_b[m];             // team-uniform
    const int total = sa + sb;

    const int NV = LEN_OUT >> 2;            // int4s per row (4128)
    const int nA = sa >> 2;                 // int4s fully inside A
    const int nT = (total + 3) >> 2;        // first int4 fully inside tail

    const int* a_row = a   + (size_t)g * LEN_A;
    const int* d_row = dst + (size_t)m * LEN_OUT;
    const int* b_row = b   + (size_t)m * LEN_B;
    int*       o_row = out + (size_t)m * LEN_OUT;

    const v4i* a4 = (const v4i*)a_row;
    const v4i* d4 = (const v4i*)d_row;
    v4i*       o4 = (v4i*)o_row;

    // ---- A region: cached loads (reused by 4 teams), streaming stores ----
#pragma unroll 4
    for (int vc = tid; vc < nA; vc += 256) {
        v4i v = a4[vc];
        __builtin_nontemporal_store(v, &o4[vc]);
    }

    // ---- tail region: pure streaming copy dst -> out ----
#pragma unroll 4
    for (int vc = nT + tid; vc < NV; vc += 256) {
        v4i v = __builtin_nontemporal_load(&d4[vc]);
        __builtin_nontemporal_store(v, &o4[vc]);
    }

    // ---- mixed region [nA, nT): ~ (sb/4 + 2) int4s per row, scalar ----
    for (int vc = nA + tid; vc < nT; vc += 256) {
        const int j0 = vc << 2;
        v4i v;
#pragma unroll
        for (int k = 0; k < 4; ++k) {
            const int j = j0 + k;
            int val;
            if (j < sa)         val = a_row[j];
            else if (j < total) val = b_row[j - sa];
            else                val = d_row[j];
            v[k] = val;
        }
        __builtin_nontemporal_store(v, &o4[vc]);
    }
}

extern "C" void kernel_launch(void* const* d_in, const int* in_sizes, int n_in,
                              void* d_out, int out_size, void* d_ws, size_t ws_size,
                              hipStream_t stream) {
    const int* dst   = (const int*)d_in[0];  // (M, LEN_OUT)
    const int* a     = (const int*)d_in[1];  // (BS, LEN_A)
    const int* b     = (const int*)d_in[2];  // (M, LEN_B)
    const int* seq_a = (const int*)d_in[3];  // (BS,)
    const int* seq_b = (const int*)d_in[4];  // (M,)
    int* out = (int*)d_out;

    const int BS      = in_sizes[3];          // 512
    const int M       = in_sizes[4];          // 2048
    const int LEN_A   = in_sizes[1] / BS;     // 16384
    const int LEN_B   = in_sizes[2] / M;      // 128
    const int LEN_OUT = in_sizes[0] / M;      // 16512
    const int repeat  = M / BS;               // 4

    dim3 block(256 * repeat);                 // 1024: 4 teams x 256
    dim3 grid(BS);                            // one block per row-group
    splice_kernel<<<grid, block, 0, stream>>>(dst, a, b, seq_a, seq_b, out,
                                              LEN_OUT, LEN_A, LEN_B, repeat);
}